// Round 1
// baseline (685.416 us; speedup 1.0000x reference)
//
#include <hip/hip_runtime.h>

typedef float f4 __attribute__((ext_vector_type(4)));

// out[M,128] = A[M,128] @ W[128,128]  (f32 vector-ALU GEMM, K=N=128)
// Safe for out==A: each block stages its own 64-row tile to LDS before writing.
__global__ __launch_bounds__(256) void gemm_k128(const float* __restrict__ A,
                                                 const float* __restrict__ W,
                                                 float* __restrict__ out, int M) {
  __shared__ f4 w_lds[128 * 32];  // W[k][c], 64 KB
  __shared__ f4 a_lds[64 * 32];   // A-tile, 32 KB
  const int t = threadIdx.x;

  // load W (4096 f4), coalesced
  for (int i = t; i < 128 * 32; i += 256) w_lds[i] = ((const f4*)W)[i];

  const int row0 = blockIdx.x * 64;
  const int rows = min(64, M - row0);

  // stage A tile (2048 f4)
  for (int i = t; i < 64 * 32; i += 256) {
    int r = i >> 5;
    f4 v = {0.f, 0.f, 0.f, 0.f};
    if (r < rows) v = ((const f4*)(A + (size_t)(row0 + r) * 128))[i & 31];
    a_lds[i] = v;
  }
  __syncthreads();

  const int cg = t & 31;         // cols cg*4 .. cg*4+3
  const int r0 = (t >> 5) << 3;  // 8 rows per thread
  f4 acc[8] = {};

  for (int k = 0; k < 128; k += 4) {
    f4 w0 = w_lds[(k + 0) * 32 + cg];
    f4 w1 = w_lds[(k + 1) * 32 + cg];
    f4 w2 = w_lds[(k + 2) * 32 + cg];
    f4 w3 = w_lds[(k + 3) * 32 + cg];
#pragma unroll
    for (int i = 0; i < 8; ++i) {
      f4 a = a_lds[(r0 + i) * 32 + (k >> 2)];
      acc[i] += a.x * w0 + a.y * w1 + a.z * w2 + a.w * w3;
    }
  }

#pragma unroll
  for (int i = 0; i < 8; ++i) {
    int r = r0 + i;
    if (r < rows) *((f4*)(out + (size_t)(row0 + r) * 128) + cg) = acc[i];
  }
}

// One wave per edge (grid-stride). lane covers dims [2*lane, 2*lane+1].
__global__ __launch_bounds__(256) void edge_attn_agg(
    const int* __restrict__ edges, int n_edge,
    const float* __restrict__ hidden,
    const float* __restrict__ rela,
    const float* __restrict__ As,
    const float* __restrict__ Ar,
    const float* __restrict__ w_alpha,
    const float* __restrict__ w_alpha_b,
    float* __restrict__ agg) {
  const int lane = threadIdx.x & 63;
  const int wid = (int)((blockIdx.x * blockDim.x + threadIdx.x) >> 6);
  const int nw = (int)((gridDim.x * blockDim.x) >> 6);
  const float2 wa = *(const float2*)(w_alpha + lane * 2);
  const float bb = w_alpha_b[0];

  for (int e = wid; e < n_edge; e += nw) {
    const int rel = edges[e * 6 + 2];
    const int sub = edges[e * 6 + 4];
    const int obj = edges[e * 6 + 5];

    const float2 a = *(const float2*)(As + (size_t)sub * 128 + lane * 2);
    const float2 r = *(const float2*)(Ar + (size_t)rel * 128 + lane * 2);
    float p = fmaxf(a.x + r.x, 0.f) * wa.x + fmaxf(a.y + r.y, 0.f) * wa.y;
#pragma unroll
    for (int off = 32; off > 0; off >>= 1) p += __shfl_xor(p, off, 64);
    const float alpha = 1.f / (1.f + __expf(-(p + bb)));

    const float2 h = *(const float2*)(hidden + (size_t)sub * 128 + lane * 2);
    const float2 hr = *(const float2*)(rela + (size_t)rel * 128 + lane * 2);
    float* dst = agg + (size_t)obj * 128 + lane * 2;
    unsafeAtomicAdd(dst, alpha * (h.x + hr.x));
    unsafeAtomicAdd(dst + 1, alpha * (h.y + hr.y));
  }
}

extern "C" void kernel_launch(void* const* d_in, const int* in_sizes, int n_in,
                              void* d_out, int out_size, void* d_ws, size_t ws_size,
                              hipStream_t stream) {
  const float* hidden = (const float*)d_in[0];
  const int* edges = (const int*)d_in[1];
  const float* rela = (const float*)d_in[4];
  const float* Ws = (const float*)d_in[5];
  const float* Wr = (const float*)d_in[6];
  const float* wa = (const float*)d_in[7];
  const float* wb = (const float*)d_in[8];
  const float* Wh = (const float*)d_in[9];

  const int M = in_sizes[0] / 128;       // n_node
  const int n_edge = in_sizes[1] / 6;    // 640000
  const int relv = in_sizes[4] / 128;    // rel vocab

  float* As = (float*)d_ws;                   // M x 128
  float* Ar = As + (size_t)M * 128;           // relv x 128
  float* out = (float*)d_out;

  // agg lives in d_out (zeroed here); final GEMM is done in-place.
  hipMemsetAsync(d_out, 0, (size_t)out_size * sizeof(float), stream);

  gemm_k128<<<(M + 63) / 64, 256, 0, stream>>>(hidden, Ws, As, M);
  gemm_k128<<<(relv + 63) / 64, 256, 0, stream>>>(rela, Wr, Ar, relv);
  edge_attn_agg<<<8192, 256, 0, stream>>>(edges, n_edge, hidden, rela, As, Ar,
                                          wa, wb, out);
  gemm_k128<<<(M + 63) / 64, 256, 0, stream>>>(out, Wh, out, M);
}

// Round 2
// 405.883 us; speedup vs baseline: 1.6887x; 1.6887x over previous
//
#include <hip/hip_runtime.h>

typedef float f4 __attribute__((ext_vector_type(4)));

__device__ inline float bf2f(unsigned short u) {
  return __uint_as_float(((unsigned)u) << 16);
}
__device__ inline unsigned short f2bf(float f) {
  unsigned u = __float_as_uint(f);
  return (unsigned short)((u + 0x7FFF + ((u >> 16) & 1)) >> 16);
}

// out[M,128] = A[M,128] @ W[128,128]  (f32 vector-ALU GEMM, K=N=128)
// Safe for out==A: each block stages its own 64-row tile to LDS before writing.
template <bool BFOUT>
__global__ __launch_bounds__(256) void gemm_k128(const float* __restrict__ A,
                                                 const float* __restrict__ W,
                                                 void* __restrict__ outp, int M) {
  __shared__ f4 w_lds[128 * 32];  // W[k][c], 64 KB
  __shared__ f4 a_lds[64 * 32];   // A-tile, 32 KB
  const int t = threadIdx.x;

  for (int i = t; i < 128 * 32; i += 256) w_lds[i] = ((const f4*)W)[i];

  const int row0 = blockIdx.x * 64;
  const int rows = min(64, M - row0);

  for (int i = t; i < 64 * 32; i += 256) {
    int r = i >> 5;
    f4 v = {0.f, 0.f, 0.f, 0.f};
    if (r < rows) v = ((const f4*)(A + (size_t)(row0 + r) * 128))[i & 31];
    a_lds[i] = v;
  }
  __syncthreads();

  const int cg = t & 31;
  const int r0 = (t >> 5) << 3;
  f4 acc[8] = {};

  for (int k = 0; k < 128; k += 4) {
    f4 w0 = w_lds[(k + 0) * 32 + cg];
    f4 w1 = w_lds[(k + 1) * 32 + cg];
    f4 w2 = w_lds[(k + 2) * 32 + cg];
    f4 w3 = w_lds[(k + 3) * 32 + cg];
#pragma unroll
    for (int i = 0; i < 8; ++i) {
      f4 a = a_lds[(r0 + i) * 32 + (k >> 2)];
      acc[i] += a.x * w0 + a.y * w1 + a.z * w2 + a.w * w3;
    }
  }

#pragma unroll
  for (int i = 0; i < 8; ++i) {
    int r = r0 + i;
    if (r < rows) {
      if (BFOUT) {
        ushort4 o;
        o.x = f2bf(acc[i].x); o.y = f2bf(acc[i].y);
        o.z = f2bf(acc[i].z); o.w = f2bf(acc[i].w);
        *((ushort4*)((unsigned short*)outp + (size_t)(row0 + r) * 128) + cg) = o;
      } else {
        *((f4*)((float*)outp + (size_t)(row0 + r) * 128) + cg) = acc[i];
      }
    }
  }
}

__global__ __launch_bounds__(256) void hist_kernel(const int* __restrict__ edges,
                                                   int n_edge, int* __restrict__ counts) {
  int e = blockIdx.x * 256 + threadIdx.x;
  if (e < n_edge) atomicAdd(&counts[edges[e * 6 + 5]], 1);
}

// single-workgroup exclusive scan of counts[0..n) -> offsets[0..n], cursor copy
__global__ __launch_bounds__(1024) void exscan_kernel(const int* __restrict__ counts,
                                                      int* __restrict__ offsets,
                                                      int* __restrict__ cursor, int n) {
  const int t = threadIdx.x;
  const int CH = (n + 1023) / 1024;
  const int base = t * CH;

  int sum = 0;
  for (int i = 0; i < CH; ++i) {
    int idx = base + i;
    if (idx < n) sum += counts[idx];
  }

  // inclusive wave scan
  int s = sum;
  const int lane = t & 63, w = t >> 6;
  for (int off = 1; off < 64; off <<= 1) {
    int o = __shfl_up(s, off, 64);
    if (lane >= off) s += o;
  }
  __shared__ int wsum[16];
  if (lane == 63) wsum[w] = s;
  __syncthreads();
  if (w == 0 && lane < 16) {
    int v = wsum[lane];
    for (int off = 1; off < 16; off <<= 1) {
      int o = __shfl_up(v, off, 64);
      if (lane >= off) v += o;
    }
    wsum[lane] = v;
  }
  __syncthreads();
  const int wprefix = (w > 0) ? wsum[w - 1] : 0;
  int run = wprefix + (s - sum);  // exclusive prefix of this thread

  for (int i = 0; i < CH; ++i) {
    int idx = base + i;
    if (idx < n) {
      offsets[idx] = run;
      cursor[idx] = run;
      run += counts[idx];
    }
  }
  if (t == 1023) offsets[n] = wprefix + s;
}

__global__ __launch_bounds__(256) void scatter_kernel(const int* __restrict__ edges,
                                                      int n_edge, int* __restrict__ cursor,
                                                      int2* __restrict__ esr) {
  int e = blockIdx.x * 256 + threadIdx.x;
  if (e < n_edge) {
    int rel = edges[e * 6 + 2];
    int sub = edges[e * 6 + 4];
    int obj = edges[e * 6 + 5];
    int pos = atomicAdd(&cursor[obj], 1);
    esr[pos] = make_int2(sub, rel);
  }
}

// One wave per node. Two 32-lane halves, each processes one incoming edge
// per iteration (float4 per lane over 128 dims). No float atomics.
__global__ __launch_bounds__(256) void node_agg(
    const int* __restrict__ offsets, const int2* __restrict__ esr,
    const float* __restrict__ hidden, const float* __restrict__ rela,
    const unsigned short* __restrict__ Asb, const unsigned short* __restrict__ Arb,
    const float* __restrict__ w_alpha, const float* __restrict__ w_b,
    float* __restrict__ out, int n_node) {
  const int lane = threadIdx.x & 63;
  const int half = lane >> 5;
  const int hl = lane & 31;
  const int wid = (int)((blockIdx.x * blockDim.x + threadIdx.x) >> 6);
  const int nw = (int)((gridDim.x * blockDim.x) >> 6);

  const f4 wa = *((const f4*)w_alpha + hl);
  const float bb = w_b[0];

  for (int n = wid; n < n_node; n += nw) {
    const int beg = offsets[n], end = offsets[n + 1];
    f4 acc = {0.f, 0.f, 0.f, 0.f};

    for (int i = beg + half; i < end; i += 2) {
      const int2 sr = esr[i];  // (sub, rel) broadcast within half
      const size_t sb = (size_t)sr.x * 128, rb = (size_t)sr.y * 128;

      ushort4 as = *(const ushort4*)(Asb + sb + hl * 4);
      ushort4 ar = *(const ushort4*)(Arb + rb + hl * 4);
      f4 h = *((const f4*)(hidden + sb) + hl);
      f4 r = *((const f4*)(rela + rb) + hl);

      float p = fmaxf(bf2f(as.x) + bf2f(ar.x), 0.f) * wa.x +
                fmaxf(bf2f(as.y) + bf2f(ar.y), 0.f) * wa.y +
                fmaxf(bf2f(as.z) + bf2f(ar.z), 0.f) * wa.z +
                fmaxf(bf2f(as.w) + bf2f(ar.w), 0.f) * wa.w;
#pragma unroll
      for (int off = 16; off > 0; off >>= 1) p += __shfl_xor(p, off, 64);
      const float alpha = 1.f / (1.f + __expf(-(p + bb)));

      acc += alpha * (h + r);
    }

    // combine the two halves
    acc.x += __shfl_xor(acc.x, 32, 64);
    acc.y += __shfl_xor(acc.y, 32, 64);
    acc.z += __shfl_xor(acc.z, 32, 64);
    acc.w += __shfl_xor(acc.w, 32, 64);
    if (half == 0) *((f4*)(out + (size_t)n * 128) + hl) = acc;
  }
}

extern "C" void kernel_launch(void* const* d_in, const int* in_sizes, int n_in,
                              void* d_out, int out_size, void* d_ws, size_t ws_size,
                              hipStream_t stream) {
  const float* hidden = (const float*)d_in[0];
  const int* edges = (const int*)d_in[1];
  const float* rela = (const float*)d_in[4];
  const float* Ws = (const float*)d_in[5];
  const float* Wr = (const float*)d_in[6];
  const float* wa = (const float*)d_in[7];
  const float* wb = (const float*)d_in[8];
  const float* Wh = (const float*)d_in[9];

  const int M = in_sizes[0] / 128;     // n_node = 50000
  const int n_edge = in_sizes[1] / 6;  // 640000
  const int relv = in_sizes[4] / 128;  // 1003

  // workspace layout (bytes)
  char* ws = (char*)d_ws;
  unsigned short* Asb = (unsigned short*)ws;                       // M*128*2
  unsigned short* Arb = (unsigned short*)(ws + (size_t)M * 256);   // relv*128*2
  char* p = ws + (size_t)M * 256 + (size_t)relv * 256;
  p = (char*)(((size_t)p + 255) & ~(size_t)255);
  int2* esr = (int2*)p;                 // n_edge * 8
  int* counts = (int*)(p + (size_t)n_edge * 8);       // M
  int* offsets = counts + M;                          // M+1
  int* cursor = offsets + M + 1;                      // M
  float* out = (float*)d_out;

  hipMemsetAsync(counts, 0, (size_t)M * sizeof(int), stream);

  gemm_k128<true><<<(M + 63) / 64, 256, 0, stream>>>(hidden, Ws, Asb, M);
  gemm_k128<true><<<(relv + 63) / 64, 256, 0, stream>>>(rela, Wr, Arb, relv);

  hist_kernel<<<(n_edge + 255) / 256, 256, 0, stream>>>(edges, n_edge, counts);
  exscan_kernel<<<1, 1024, 0, stream>>>(counts, offsets, cursor, M);
  scatter_kernel<<<(n_edge + 255) / 256, 256, 0, stream>>>(edges, n_edge, cursor, esr);

  node_agg<<<(M * 64 + 255) / 256, 256, 0, stream>>>(offsets, esr, hidden, rela,
                                                     Asb, Arb, wa, wb, out, M);

  gemm_k128<false><<<(M + 63) / 64, 256, 0, stream>>>(out, Wh, d_out, M);
}

// Round 3
// 250.033 us; speedup vs baseline: 2.7413x; 1.6233x over previous
//
#include <hip/hip_runtime.h>

typedef float f4 __attribute__((ext_vector_type(4)));

__device__ inline float bf2f(unsigned short u) {
  return __uint_as_float(((unsigned)u) << 16);
}
__device__ inline unsigned short f2bf(float f) {
  unsigned u = __float_as_uint(f);
  return (unsigned short)((u + 0x7FFF + ((u >> 16) & 1)) >> 16);
}

// out[M,128] = A[M,128] @ W[128,128]  (f32 vector-ALU GEMM, K=N=128)
// 512 threads, 64-row tile, 4 rows x 4 cols per thread -> 2 waves/SIMD.
// Safe for out==A: block stages its tile to LDS before writing.
template <bool BFOUT>
__global__ __launch_bounds__(512) void gemm_k128(const float* __restrict__ A,
                                                 const float* __restrict__ W,
                                                 void* __restrict__ outp, int M) {
  __shared__ f4 w_lds[128 * 32];  // 64 KB
  __shared__ f4 a_lds[64 * 32];   // 32 KB
  const int t = threadIdx.x;

  for (int i = t; i < 128 * 32; i += 512) w_lds[i] = ((const f4*)W)[i];

  const int row0 = blockIdx.x * 64;
  const int rows = min(64, M - row0);

  for (int i = t; i < 64 * 32; i += 512) {
    int r = i >> 5;
    f4 v = {0.f, 0.f, 0.f, 0.f};
    if (r < rows) v = ((const f4*)(A + (size_t)(row0 + r) * 128))[i & 31];
    a_lds[i] = v;
  }
  __syncthreads();

  const int cg = t & 31;
  const int r0 = (t >> 5) << 2;  // 4 rows per thread
  f4 acc[4] = {};

  for (int k = 0; k < 128; k += 4) {
    f4 w0 = w_lds[(k + 0) * 32 + cg];
    f4 w1 = w_lds[(k + 1) * 32 + cg];
    f4 w2 = w_lds[(k + 2) * 32 + cg];
    f4 w3 = w_lds[(k + 3) * 32 + cg];
#pragma unroll
    for (int i = 0; i < 4; ++i) {
      f4 a = a_lds[(r0 + i) * 32 + (k >> 2)];
      acc[i] += a.x * w0 + a.y * w1 + a.z * w2 + a.w * w3;
    }
  }

#pragma unroll
  for (int i = 0; i < 4; ++i) {
    int r = r0 + i;
    if (r < rows) {
      if (BFOUT) {
        ushort4 o;
        o.x = f2bf(acc[i].x); o.y = f2bf(acc[i].y);
        o.z = f2bf(acc[i].z); o.w = f2bf(acc[i].w);
        *((ushort4*)((unsigned short*)outp + (size_t)(row0 + r) * 128) + cg) = o;
      } else {
        *((f4*)((float*)outp + (size_t)(row0 + r) * 128) + cg) = acc[i];
      }
    }
  }
}

__global__ __launch_bounds__(256) void hist_kernel(const int* __restrict__ edges,
                                                   int n_edge, int* __restrict__ counts) {
  int e = blockIdx.x * 256 + threadIdx.x;
  if (e < n_edge) atomicAdd(&counts[edges[e * 6 + 5]], 1);
}

// ---- 3-kernel parallel exclusive scan over counts[0..M) ----
__global__ __launch_bounds__(256) void scan_reduce(const int* __restrict__ counts,
                                                   int M, int* __restrict__ bsums) {
  int idx = blockIdx.x * 256 + threadIdx.x;
  int v = (idx < M) ? counts[idx] : 0;
#pragma unroll
  for (int off = 32; off; off >>= 1) v += __shfl_xor(v, off, 64);
  __shared__ int wsum[4];
  if ((threadIdx.x & 63) == 0) wsum[threadIdx.x >> 6] = v;
  __syncthreads();
  if (threadIdx.x == 0) bsums[blockIdx.x] = wsum[0] + wsum[1] + wsum[2] + wsum[3];
}

__global__ __launch_bounds__(256) void scan_sums(const int* __restrict__ bsums,
                                                 int NB, int* __restrict__ bpref) {
  const int t = threadIdx.x;
  int v = (t < NB) ? bsums[t] : 0;
  const int lane = t & 63, w = t >> 6;
  int s = v;
  for (int off = 1; off < 64; off <<= 1) {
    int o = __shfl_up(s, off, 64);
    if (lane >= off) s += o;
  }
  __shared__ int wsum[4], wpre[4];
  if (lane == 63) wsum[w] = s;
  __syncthreads();
  if (t == 0) {
    int r = 0;
    for (int i = 0; i < 4; ++i) { wpre[i] = r; r += wsum[i]; }
  }
  __syncthreads();
  if (t < NB) bpref[t] = wpre[w] + s - v;
}

__global__ __launch_bounds__(256) void scan_final(const int* __restrict__ counts,
                                                  int M, int n_edge,
                                                  const int* __restrict__ bpref,
                                                  int* __restrict__ offsets,
                                                  int* __restrict__ cursor) {
  const int t = threadIdx.x;
  const int idx = blockIdx.x * 256 + t;
  int c = (idx < M) ? counts[idx] : 0;
  const int lane = t & 63, w = t >> 6;
  int s = c;
  for (int off = 1; off < 64; off <<= 1) {
    int o = __shfl_up(s, off, 64);
    if (lane >= off) s += o;
  }
  __shared__ int wsum[4], wpre[4];
  if (lane == 63) wsum[w] = s;
  __syncthreads();
  if (t == 0) {
    int r = 0;
    for (int i = 0; i < 4; ++i) { wpre[i] = r; r += wsum[i]; }
  }
  __syncthreads();
  int excl = bpref[blockIdx.x] + wpre[w] + s - c;
  if (idx < M) { offsets[idx] = excl; cursor[idx] = excl; }
  if (idx == 0) offsets[M] = n_edge;
}

__global__ __launch_bounds__(256) void scatter_kernel(const int* __restrict__ edges,
                                                      int n_edge, int* __restrict__ cursor,
                                                      int2* __restrict__ esr) {
  int e = blockIdx.x * 256 + threadIdx.x;
  if (e < n_edge) {
    int rel = edges[e * 6 + 2];
    int sub = edges[e * 6 + 4];
    int obj = edges[e * 6 + 5];
    int pos = atomicAdd(&cursor[obj], 1);
    esr[pos] = make_int2(sub, rel);
  }
}

// One wave per node. Two 32-lane halves, each processes one incoming edge
// per iteration (float4 per lane over 128 dims). No float atomics.
__global__ __launch_bounds__(256) void node_agg(
    const int* __restrict__ offsets, const int2* __restrict__ esr,
    const float* __restrict__ hidden, const float* __restrict__ rela,
    const unsigned short* __restrict__ Asb, const unsigned short* __restrict__ Arb,
    const float* __restrict__ w_alpha, const float* __restrict__ w_b,
    float* __restrict__ out, int n_node) {
  const int lane = threadIdx.x & 63;
  const int half = lane >> 5;
  const int hl = lane & 31;
  const int wid = (int)((blockIdx.x * blockDim.x + threadIdx.x) >> 6);
  const int nw = (int)((gridDim.x * blockDim.x) >> 6);

  const f4 wa = *((const f4*)w_alpha + hl);
  const float bb = w_b[0];

  for (int n = wid; n < n_node; n += nw) {
    const int beg = offsets[n], end = offsets[n + 1];
    f4 acc = {0.f, 0.f, 0.f, 0.f};

    for (int i = beg + half; i < end; i += 2) {
      const int2 sr = esr[i];
      const size_t sb = (size_t)sr.x * 128, rb = (size_t)sr.y * 128;

      ushort4 as = *(const ushort4*)(Asb + sb + hl * 4);
      ushort4 ar = *(const ushort4*)(Arb + rb + hl * 4);
      f4 h = *((const f4*)(hidden + sb) + hl);
      f4 r = *((const f4*)(rela + rb) + hl);

      float p = fmaxf(bf2f(as.x) + bf2f(ar.x), 0.f) * wa.x +
                fmaxf(bf2f(as.y) + bf2f(ar.y), 0.f) * wa.y +
                fmaxf(bf2f(as.z) + bf2f(ar.z), 0.f) * wa.z +
                fmaxf(bf2f(as.w) + bf2f(ar.w), 0.f) * wa.w;
#pragma unroll
      for (int off = 16; off > 0; off >>= 1) p += __shfl_xor(p, off, 64);
      const float alpha = 1.f / (1.f + __expf(-(p + bb)));

      acc += alpha * (h + r);
    }

    acc.x += __shfl_xor(acc.x, 32, 64);
    acc.y += __shfl_xor(acc.y, 32, 64);
    acc.z += __shfl_xor(acc.z, 32, 64);
    acc.w += __shfl_xor(acc.w, 32, 64);
    if (half == 0) *((f4*)(out + (size_t)n * 128) + hl) = acc;
  }
}

extern "C" void kernel_launch(void* const* d_in, const int* in_sizes, int n_in,
                              void* d_out, int out_size, void* d_ws, size_t ws_size,
                              hipStream_t stream) {
  const float* hidden = (const float*)d_in[0];
  const int* edges = (const int*)d_in[1];
  const float* rela = (const float*)d_in[4];
  const float* Ws = (const float*)d_in[5];
  const float* Wr = (const float*)d_in[6];
  const float* wa = (const float*)d_in[7];
  const float* wb = (const float*)d_in[8];
  const float* Wh = (const float*)d_in[9];

  const int M = in_sizes[0] / 128;     // n_node = 50000
  const int n_edge = in_sizes[1] / 6;  // 640000
  const int relv = in_sizes[4] / 128;  // 1003
  const int NB = (M + 255) / 256;      // 196 scan blocks

  // workspace layout
  char* ws = (char*)d_ws;
  unsigned short* Asb = (unsigned short*)ws;                      // M*128*2
  unsigned short* Arb = (unsigned short*)(ws + (size_t)M * 256);  // relv*128*2
  char* p = ws + (size_t)M * 256 + (size_t)relv * 256;
  p = (char*)(((size_t)p + 255) & ~(size_t)255);
  int2* esr = (int2*)p;                          // n_edge * 8
  int* counts = (int*)(p + (size_t)n_edge * 8);  // M
  int* offsets = counts + M;                     // M+1
  int* cursor = offsets + M + 1;                 // M
  int* bsums = cursor + M;                       // NB
  int* bpref = bsums + NB;                       // NB
  float* out = (float*)d_out;

  hipMemsetAsync(counts, 0, (size_t)M * sizeof(int), stream);

  gemm_k128<true><<<(M + 63) / 64, 512, 0, stream>>>(hidden, Ws, Asb, M);
  gemm_k128<true><<<(relv + 63) / 64, 512, 0, stream>>>(rela, Wr, Arb, relv);

  hist_kernel<<<(n_edge + 255) / 256, 256, 0, stream>>>(edges, n_edge, counts);
  scan_reduce<<<NB, 256, 0, stream>>>(counts, M, bsums);
  scan_sums<<<1, 256, 0, stream>>>(bsums, NB, bpref);
  scan_final<<<NB, 256, 0, stream>>>(counts, M, n_edge, bpref, offsets, cursor);
  scatter_kernel<<<(n_edge + 255) / 256, 256, 0, stream>>>(edges, n_edge, cursor, esr);

  node_agg<<<(M * 64 + 255) / 256, 256, 0, stream>>>(offsets, esr, hidden, rela,
                                                     Asb, Arb, wa, wb, out, M);

  gemm_k128<false><<<(M + 63) / 64, 512, 0, stream>>>(out, Wh, d_out, M);
}

// Round 4
// 171.981 us; speedup vs baseline: 3.9854x; 1.4538x over previous
//
#include <hip/hip_runtime.h>

typedef float f4 __attribute__((ext_vector_type(4)));
typedef float f32x4 __attribute__((ext_vector_type(4)));
typedef short bf16x8 __attribute__((ext_vector_type(8)));
typedef unsigned short u16x8 __attribute__((ext_vector_type(8)));

__device__ inline float bf2f(unsigned short u) {
  return __uint_as_float(((unsigned)u) << 16);
}
__device__ inline unsigned short f2bf(float f) {
  unsigned u = __float_as_uint(f);
  return (unsigned short)((u + 0x7FFF + ((u >> 16) & 1)) >> 16);
}
__device__ inline u16x8 cvt8(const float* __restrict__ src) {
  f4 lo = *(const f4*)src, hi = *(const f4*)(src + 4);
  u16x8 v;
  v[0] = f2bf(lo.x); v[1] = f2bf(lo.y); v[2] = f2bf(lo.z); v[3] = f2bf(lo.w);
  v[4] = f2bf(hi.x); v[5] = f2bf(hi.y); v[6] = f2bf(hi.z); v[7] = f2bf(hi.w);
  return v;
}

// Fused: hidden->bf16 (interleaved into d_out slot bytes [256,512) per row),
// rela->bf16, 3x weight transpose+convert, edge histogram.
__global__ __launch_bounds__(256) void prep(
    const float* __restrict__ hidden, const float* __restrict__ rela,
    const float* __restrict__ Ws, const float* __restrict__ Wr,
    const float* __restrict__ Wh, const int* __restrict__ edges, int n_edge,
    char* __restrict__ dout, unsigned short* __restrict__ Rb,
    unsigned short* __restrict__ WsT, unsigned short* __restrict__ WrT,
    unsigned short* __restrict__ WhT, int* __restrict__ counts, int M, int relv) {
  const int t = threadIdx.x;
  const int BH = (M * 16 + 255) >> 8;
  const int BR = (relv * 16 + 255) >> 8;
  int b = blockIdx.x;
  if (b < BH) {
    int c = b * 256 + t;
    if (c < M * 16) {
      int row = c >> 4, part = c & 15;
      u16x8 v = cvt8(hidden + (size_t)row * 128 + part * 8);
      *(u16x8*)(dout + (size_t)row * 512 + 256 + part * 16) = v;
    }
    return;
  }
  b -= BH;
  if (b < BR) {
    int c = b * 256 + t;
    if (c < relv * 16) {
      int row = c >> 4, part = c & 15;
      u16x8 v = cvt8(rela + (size_t)row * 128 + part * 8);
      *(u16x8*)((char*)Rb + (size_t)c * 16) = v;
    }
    return;
  }
  b -= BR;
  if (b < 192) {
    int wsel = b >> 6;
    const float* W = wsel == 0 ? Ws : (wsel == 1 ? Wr : Wh);
    unsigned short* WT = wsel == 0 ? WsT : (wsel == 1 ? WrT : WhT);
    int e = (b & 63) * 256 + t;  // 0..16383
    int cc = e >> 7, kk = e & 127;
    WT[e] = f2bf(W[kk * 128 + cc]);  // WT[c][k] = W[k][c]
    return;
  }
  b -= 192;
  int e = b * 256 + t;
  if (e < n_edge) atomicAdd(&counts[edges[e * 6 + 5]], 1);
}

// out[M,128] = A_bf16[M,128] @ W  using WT (bf16, [c][k]) and MFMA 16x16x32.
// 64-row tile, 4 waves, both LDS tiles XOR-swizzled (byte ^= (row&7)<<4).
// A is staged fully to LDS before any store -> safe for in-place (gemm3).
template <bool BFOUT>
__global__ __launch_bounds__(256) void gemm_mfma(const char* __restrict__ Ab, int aStride,
                                                 const unsigned short* __restrict__ WT,
                                                 char* __restrict__ outB, int M) {
  __shared__ __align__(16) char lds[49152];  // A tile 16K | W^T 32K
  const int t = threadIdx.x;
  const int row0 = blockIdx.x * 64;
#pragma unroll
  for (int i = 0; i < 8; ++i) {
    int m = i * 256 + t;
    u16x8 v = ((const u16x8*)WT)[m];
    *(u16x8*)(lds + 16384 + ((m * 16) ^ (((m >> 4) & 7) << 4))) = v;
  }
#pragma unroll
  for (int i = 0; i < 4; ++i) {
    int m = i * 256 + t;
    int r = m >> 4;
    int gr = row0 + r;
    if (gr > M - 1) gr = M - 1;
    u16x8 v = *(const u16x8*)(Ab + (size_t)gr * aStride + (m & 15) * 16);
    *(u16x8*)(lds + ((m * 16) ^ ((r & 7) << 4))) = v;
  }
  __syncthreads();

  const int w = t >> 6, l = t & 63, lr = l & 15, lg = l >> 4;
  const int rowA = w * 16 + lr;
  f32x4 acc[8] = {};
#pragma unroll
  for (int k0 = 0; k0 < 4; ++k0) {
    int kb = k0 * 64 + lg * 16;
    bf16x8 a = *(const bf16x8*)(lds + rowA * 256 + (kb ^ ((rowA & 7) << 4)));
#pragma unroll
    for (int c0 = 0; c0 < 8; ++c0) {
      int cr = c0 * 16 + lr;
      bf16x8 bfr = *(const bf16x8*)(lds + 16384 + cr * 256 + (kb ^ ((cr & 7) << 4)));
      acc[c0] = __builtin_amdgcn_mfma_f32_16x16x32_bf16(a, bfr, acc[c0], 0, 0, 0);
    }
  }
#pragma unroll
  for (int c0 = 0; c0 < 8; ++c0) {
    int col = c0 * 16 + lr;
#pragma unroll
    for (int j = 0; j < 4; ++j) {
      int grow = row0 + w * 16 + lg * 4 + j;
      if (grow < M) {
        if (BFOUT)
          *(unsigned short*)(outB + (size_t)grow * 256 + col * 2) = f2bf(acc[c0][j]);
        else
          *(float*)(outB + (size_t)grow * 512 + (size_t)col * 4) = acc[c0][j];
      }
    }
  }
}

// ---- 3-kernel parallel exclusive scan over counts[0..M) ----
__global__ __launch_bounds__(256) void scan_reduce(const int* __restrict__ counts,
                                                   int M, int* __restrict__ bsums) {
  int idx = blockIdx.x * 256 + threadIdx.x;
  int v = (idx < M) ? counts[idx] : 0;
#pragma unroll
  for (int off = 32; off; off >>= 1) v += __shfl_xor(v, off, 64);
  __shared__ int wsum[4];
  if ((threadIdx.x & 63) == 0) wsum[threadIdx.x >> 6] = v;
  __syncthreads();
  if (threadIdx.x == 0) bsums[blockIdx.x] = wsum[0] + wsum[1] + wsum[2] + wsum[3];
}

__global__ __launch_bounds__(256) void scan_sums(const int* __restrict__ bsums,
                                                 int NB, int* __restrict__ bpref) {
  const int t = threadIdx.x;
  int v = (t < NB) ? bsums[t] : 0;
  const int lane = t & 63, w = t >> 6;
  int s = v;
  for (int off = 1; off < 64; off <<= 1) {
    int o = __shfl_up(s, off, 64);
    if (lane >= off) s += o;
  }
  __shared__ int wsum[4], wpre[4];
  if (lane == 63) wsum[w] = s;
  __syncthreads();
  if (t == 0) {
    int r = 0;
    for (int i = 0; i < 4; ++i) { wpre[i] = r; r += wsum[i]; }
  }
  __syncthreads();
  if (t < NB) bpref[t] = wpre[w] + s - v;
}

__global__ __launch_bounds__(256) void scan_final(const int* __restrict__ counts,
                                                  int M, int n_edge,
                                                  const int* __restrict__ bpref,
                                                  int* __restrict__ offsets,
                                                  int* __restrict__ cursor) {
  const int t = threadIdx.x;
  const int idx = blockIdx.x * 256 + t;
  int c = (idx < M) ? counts[idx] : 0;
  const int lane = t & 63, w = t >> 6;
  int s = c;
  for (int off = 1; off < 64; off <<= 1) {
    int o = __shfl_up(s, off, 64);
    if (lane >= off) s += o;
  }
  __shared__ int wsum[4], wpre[4];
  if (lane == 63) wsum[w] = s;
  __syncthreads();
  if (t == 0) {
    int r = 0;
    for (int i = 0; i < 4; ++i) { wpre[i] = r; r += wsum[i]; }
  }
  __syncthreads();
  int excl = bpref[blockIdx.x] + wpre[w] + s - c;
  if (idx < M) { offsets[idx] = excl; cursor[idx] = excl; }
  if (idx == 0) offsets[M] = n_edge;
}

__global__ __launch_bounds__(256) void scatter_kernel(const int* __restrict__ edges,
                                                      int n_edge, int* __restrict__ cursor,
                                                      unsigned* __restrict__ esr) {
  int e = blockIdx.x * 256 + threadIdx.x;
  if (e < n_edge) {
    int rel = edges[e * 6 + 2];
    int sub = edges[e * 6 + 4];
    int obj = edges[e * 6 + 5];
    int pos = atomicAdd(&cursor[obj], 1);
    esr[pos] = (unsigned)sub | ((unsigned)rel << 17);  // sub<2^17, rel<2^15
  }
}

// One wave per node, two 32-lane halves each own alternating edges.
// Gathers are all bf16 (256B/row). Writes bf16 agg into d_out bytes [n*512, n*512+256).
__global__ __launch_bounds__(256) void node_agg(
    const int* __restrict__ offsets, const unsigned* __restrict__ esr,
    char* __restrict__ dout, const unsigned short* __restrict__ Rb,
    const unsigned short* __restrict__ Asb, const unsigned short* __restrict__ Arb,
    const float* __restrict__ w_alpha, const float* __restrict__ w_b, int M) {
  const int lane = threadIdx.x & 63;
  const int half = lane >> 5, hl = lane & 31;
  const int n = (int)(((size_t)blockIdx.x * blockDim.x + threadIdx.x) >> 6);
  if (n >= M) return;
  const f4 wa = ((const f4*)w_alpha)[hl];
  const float bb = w_b[0];
  const int beg = offsets[n], end = offsets[n + 1];
  f4 acc = {0.f, 0.f, 0.f, 0.f};

  for (int i = beg + half; i < end; i += 2) {
    unsigned u = esr[i];
    int sub = (int)(u & 0x1FFFF), rel = (int)(u >> 17);
    ushort4 as = *(const ushort4*)(Asb + (size_t)sub * 128 + hl * 4);
    ushort4 ar = *(const ushort4*)(Arb + (size_t)rel * 128 + hl * 4);
    ushort4 h = *(const ushort4*)(dout + (size_t)sub * 512 + 256 + hl * 8);
    ushort4 r = *(const ushort4*)(Rb + (size_t)rel * 128 + hl * 4);

    float p = fmaxf(bf2f(as.x) + bf2f(ar.x), 0.f) * wa.x +
              fmaxf(bf2f(as.y) + bf2f(ar.y), 0.f) * wa.y +
              fmaxf(bf2f(as.z) + bf2f(ar.z), 0.f) * wa.z +
              fmaxf(bf2f(as.w) + bf2f(ar.w), 0.f) * wa.w;
#pragma unroll
    for (int off = 16; off > 0; off >>= 1) p += __shfl_xor(p, off, 64);
    const float alpha = 1.f / (1.f + __expf(-(p + bb)));

    f4 m = {bf2f(h.x) + bf2f(r.x), bf2f(h.y) + bf2f(r.y),
            bf2f(h.z) + bf2f(r.z), bf2f(h.w) + bf2f(r.w)};
    acc += alpha * m;
  }

  acc.x += __shfl_xor(acc.x, 32, 64);
  acc.y += __shfl_xor(acc.y, 32, 64);
  acc.z += __shfl_xor(acc.z, 32, 64);
  acc.w += __shfl_xor(acc.w, 32, 64);
  if (half == 0) {
    ushort4 o;
    o.x = f2bf(acc.x); o.y = f2bf(acc.y); o.z = f2bf(acc.z); o.w = f2bf(acc.w);
    *(ushort4*)(dout + (size_t)n * 512 + hl * 8) = o;
  }
}

extern "C" void kernel_launch(void* const* d_in, const int* in_sizes, int n_in,
                              void* d_out, int out_size, void* d_ws, size_t ws_size,
                              hipStream_t stream) {
  const float* hidden = (const float*)d_in[0];
  const int* edges = (const int*)d_in[1];
  const float* rela = (const float*)d_in[4];
  const float* Ws = (const float*)d_in[5];
  const float* Wr = (const float*)d_in[6];
  const float* wa = (const float*)d_in[7];
  const float* wb = (const float*)d_in[8];
  const float* Wh = (const float*)d_in[9];

  const int M = in_sizes[0] / 128;     // 50000
  const int n_edge = in_sizes[1] / 6;  // 640000
  const int relv = in_sizes[4] / 128;  // 1003
  const int NB = (M + 255) / 256;

  char* ws = (char*)d_ws;
  unsigned short* Asb = (unsigned short*)ws;
  size_t off = (size_t)M * 256;
  unsigned short* Rb = (unsigned short*)(ws + off); off += (size_t)relv * 256;
  unsigned short* Arb = (unsigned short*)(ws + off); off += (size_t)relv * 256;
  unsigned short* WsT = (unsigned short*)(ws + off); off += 32768;
  unsigned short* WrT = (unsigned short*)(ws + off); off += 32768;
  unsigned short* WhT = (unsigned short*)(ws + off); off += 32768;
  unsigned* esr = (unsigned*)(ws + off); off += (size_t)n_edge * 4;
  int* counts = (int*)(ws + off); off += (size_t)M * 4;
  int* offsets = (int*)(ws + off); off += (size_t)(M + 1) * 4;
  int* cursor = (int*)(ws + off); off += (size_t)M * 4;
  int* bsums = (int*)(ws + off); off += 1024;
  int* bpref = (int*)(ws + off);
  char* dout = (char*)d_out;

  hipMemsetAsync(counts, 0, (size_t)M * 4, stream);

  const int BH = (M * 16 + 255) / 256, BR = (relv * 16 + 255) / 256;
  const int BE = (n_edge + 255) / 256;
  prep<<<BH + BR + 192 + BE, 256, 0, stream>>>(hidden, rela, Ws, Wr, Wh, edges,
                                               n_edge, dout, Rb, WsT, WrT, WhT,
                                               counts, M, relv);

  gemm_mfma<true><<<(M + 63) / 64, 256, 0, stream>>>(dout + 256, 512, WsT, (char*)Asb, M);
  gemm_mfma<true><<<(relv + 63) / 64, 256, 0, stream>>>((const char*)Rb, 256, WrT, (char*)Arb, relv);

  scan_reduce<<<NB, 256, 0, stream>>>(counts, M, bsums);
  scan_sums<<<1, 256, 0, stream>>>(bsums, NB, bpref);
  scan_final<<<NB, 256, 0, stream>>>(counts, M, n_edge, bpref, offsets, cursor);
  scatter_kernel<<<BE, 256, 0, stream>>>(edges, n_edge, cursor, esr);

  node_agg<<<((size_t)M * 64 + 255) / 256, 256, 0, stream>>>(offsets, esr, dout, Rb,
                                                             Asb, Arb, wa, wb, M);

  gemm_mfma<false><<<(M + 63) / 64, 256, 0, stream>>>(dout, 512, WhT, dout, M);
}

// Round 5
// 167.116 us; speedup vs baseline: 4.1014x; 1.0291x over previous
//
#include <hip/hip_runtime.h>

typedef float f4 __attribute__((ext_vector_type(4)));
typedef float f2 __attribute__((ext_vector_type(2)));
typedef float f32x4 __attribute__((ext_vector_type(4)));
typedef short bf16x8 __attribute__((ext_vector_type(8)));
typedef unsigned short u16x8 __attribute__((ext_vector_type(8)));

__device__ inline float bf2f(unsigned short u) {
  return __uint_as_float(((unsigned)u) << 16);
}
__device__ inline unsigned short f2bf(float f) {
  unsigned u = __float_as_uint(f);
  return (unsigned short)((u + 0x7FFF + ((u >> 16) & 1)) >> 16);
}
__device__ inline u16x8 cvt8(const float* __restrict__ src) {
  f4 lo = *(const f4*)src, hi = *(const f4*)(src + 4);
  u16x8 v;
  v[0] = f2bf(lo.x); v[1] = f2bf(lo.y); v[2] = f2bf(lo.z); v[3] = f2bf(lo.w);
  v[4] = f2bf(hi.x); v[5] = f2bf(hi.y); v[6] = f2bf(hi.z); v[7] = f2bf(hi.w);
  return v;
}

// Fused: hidden->bf16 into d_out record bytes [0,256); rela->bf16 into relrec
// bytes [0,256); 3x weight transpose+convert; edge histogram.
__global__ __launch_bounds__(256) void prep(
    const float* __restrict__ hidden, const float* __restrict__ rela,
    const float* __restrict__ Ws, const float* __restrict__ Wr,
    const float* __restrict__ Wh, const int* __restrict__ edges, int n_edge,
    char* __restrict__ dout, char* __restrict__ relrec,
    unsigned short* __restrict__ WsT, unsigned short* __restrict__ WrT,
    unsigned short* __restrict__ WhT, int* __restrict__ counts, int M, int relv) {
  const int t = threadIdx.x;
  const int BH = (M * 16 + 255) >> 8;
  const int BR = (relv * 16 + 255) >> 8;
  int b = blockIdx.x;
  if (b < BH) {
    int c = b * 256 + t;
    if (c < M * 16) {
      int row = c >> 4, part = c & 15;
      u16x8 v = cvt8(hidden + (size_t)row * 128 + part * 8);
      *(u16x8*)(dout + (size_t)row * 512 + part * 16) = v;
    }
    return;
  }
  b -= BH;
  if (b < BR) {
    int c = b * 256 + t;
    if (c < relv * 16) {
      int row = c >> 4, part = c & 15;
      u16x8 v = cvt8(rela + (size_t)row * 128 + part * 8);
      *(u16x8*)(relrec + (size_t)row * 512 + part * 16) = v;
    }
    return;
  }
  b -= BR;
  if (b < 192) {
    int wsel = b >> 6;
    const float* W = wsel == 0 ? Ws : (wsel == 1 ? Wr : Wh);
    unsigned short* WT = wsel == 0 ? WsT : (wsel == 1 ? WrT : WhT);
    int e = (b & 63) * 256 + t;  // 0..16383
    int cc = e >> 7, kk = e & 127;
    WT[e] = f2bf(W[kk * 128 + cc]);  // WT[c][k] = W[k][c]
    return;
  }
  b -= 192;
  int e = b * 256 + t;
  if (e < n_edge) atomicAdd(&counts[edges[e * 6 + 5]], 1);
}

// out = A_bf16[M,128] @ W via WT (bf16 [c][k]) and MFMA 16x16x32.
// MODE 0: f32 output at outB + row*outStride + col*4
// MODE 1: fp8 e4m3 output at outB + row*outStride + col
template <int MODE>
__global__ __launch_bounds__(256) void gemm_mfma(const char* __restrict__ Ab, int aStride,
                                                 const unsigned short* __restrict__ WT,
                                                 char* __restrict__ outB, int outStride,
                                                 int M) {
  __shared__ __align__(16) char lds[49152];  // A tile 16K | W^T 32K
  const int t = threadIdx.x;
  const int row0 = blockIdx.x * 64;
#pragma unroll
  for (int i = 0; i < 8; ++i) {
    int m = i * 256 + t;
    u16x8 v = ((const u16x8*)WT)[m];
    *(u16x8*)(lds + 16384 + ((m * 16) ^ (((m >> 4) & 7) << 4))) = v;
  }
#pragma unroll
  for (int i = 0; i < 4; ++i) {
    int m = i * 256 + t;
    int r = m >> 4;
    int gr = row0 + r;
    if (gr > M - 1) gr = M - 1;
    u16x8 v = *(const u16x8*)(Ab + (size_t)gr * aStride + (m & 15) * 16);
    *(u16x8*)(lds + ((m * 16) ^ ((r & 7) << 4))) = v;
  }
  __syncthreads();

  const int w = t >> 6, l = t & 63, lr = l & 15, lg = l >> 4;
  const int rowA = w * 16 + lr;
  f32x4 acc[8] = {};
#pragma unroll
  for (int k0 = 0; k0 < 4; ++k0) {
    int kb = k0 * 64 + lg * 16;
    bf16x8 a = *(const bf16x8*)(lds + rowA * 256 + (kb ^ ((rowA & 7) << 4)));
#pragma unroll
    for (int c0 = 0; c0 < 8; ++c0) {
      int cr = c0 * 16 + lr;
      bf16x8 bfr = *(const bf16x8*)(lds + 16384 + cr * 256 + (kb ^ ((cr & 7) << 4)));
      acc[c0] = __builtin_amdgcn_mfma_f32_16x16x32_bf16(a, bfr, acc[c0], 0, 0, 0);
    }
  }
#pragma unroll
  for (int c0 = 0; c0 < 8; ++c0) {
    int col = c0 * 16 + lr;
#pragma unroll
    for (int j = 0; j < 4; ++j) {
      int grow = row0 + w * 16 + lg * 4 + j;
      if (grow < M) {
        if (MODE == 0) {
          *(float*)(outB + (size_t)grow * outStride + (size_t)col * 4) = acc[c0][j];
        } else {
          unsigned pk = __builtin_amdgcn_cvt_pk_fp8_f32(acc[c0][j], acc[c0][j], 0, false);
          *(unsigned char*)(outB + (size_t)grow * outStride + col) = (unsigned char)pk;
        }
      }
    }
  }
}

// ---- 3-kernel parallel exclusive scan over counts[0..M) ----
__global__ __launch_bounds__(256) void scan_reduce(const int* __restrict__ counts,
                                                   int M, int* __restrict__ bsums) {
  int idx = blockIdx.x * 256 + threadIdx.x;
  int v = (idx < M) ? counts[idx] : 0;
#pragma unroll
  for (int off = 32; off; off >>= 1) v += __shfl_xor(v, off, 64);
  __shared__ int wsum[4];
  if ((threadIdx.x & 63) == 0) wsum[threadIdx.x >> 6] = v;
  __syncthreads();
  if (threadIdx.x == 0) bsums[blockIdx.x] = wsum[0] + wsum[1] + wsum[2] + wsum[3];
}

__global__ __launch_bounds__(256) void scan_sums(const int* __restrict__ bsums,
                                                 int NB, int* __restrict__ bpref) {
  const int t = threadIdx.x;
  int v = (t < NB) ? bsums[t] : 0;
  const int lane = t & 63, w = t >> 6;
  int s = v;
  for (int off = 1; off < 64; off <<= 1) {
    int o = __shfl_up(s, off, 64);
    if (lane >= off) s += o;
  }
  __shared__ int wsum[4], wpre[4];
  if (lane == 63) wsum[w] = s;
  __syncthreads();
  if (t == 0) {
    int r = 0;
    for (int i = 0; i < 4; ++i) { wpre[i] = r; r += wsum[i]; }
  }
  __syncthreads();
  if (t < NB) bpref[t] = wpre[w] + s - v;
}

__global__ __launch_bounds__(256) void scan_final(const int* __restrict__ counts,
                                                  int M, int n_edge,
                                                  const int* __restrict__ bpref,
                                                  int* __restrict__ offsets,
                                                  int* __restrict__ cursor) {
  const int t = threadIdx.x;
  const int idx = blockIdx.x * 256 + t;
  int c = (idx < M) ? counts[idx] : 0;
  const int lane = t & 63, w = t >> 6;
  int s = c;
  for (int off = 1; off < 64; off <<= 1) {
    int o = __shfl_up(s, off, 64);
    if (lane >= off) s += o;
  }
  __shared__ int wsum[4], wpre[4];
  if (lane == 63) wsum[w] = s;
  __syncthreads();
  if (t == 0) {
    int r = 0;
    for (int i = 0; i < 4; ++i) { wpre[i] = r; r += wsum[i]; }
  }
  __syncthreads();
  int excl = bpref[blockIdx.x] + wpre[w] + s - c;
  if (idx < M) { offsets[idx] = excl; cursor[idx] = excl; }
  if (idx == 0) offsets[M] = n_edge;
}

__global__ __launch_bounds__(256) void scatter_kernel(const int* __restrict__ edges,
                                                      int n_edge, int* __restrict__ cursor,
                                                      unsigned* __restrict__ esr) {
  int e = blockIdx.x * 256 + threadIdx.x;
  if (e < n_edge) {
    int2 a = *(const int2*)(edges + (size_t)e * 6 + 2);  // rel, 0
    int2 b = *(const int2*)(edges + (size_t)e * 6 + 4);  // sub, obj
    int pos = atomicAdd(&cursor[b.y], 1);
    esr[pos] = (unsigned)b.x | ((unsigned)a.x << 17);  // sub<2^17, rel<2^15
  }
}

// One wave per node, two 32-lane halves own alternating edges.
// Per-sub record (in dout): h_bf16 [0,256) | As_fp8 [256,384).
// Per-rel record (relrec):  r_bf16 [0,256) | Ar_fp8 [256,384).
// Writes bf16 agg row (256B) to aggB.
__global__ __launch_bounds__(256) void node_agg(
    const int* __restrict__ offsets, const unsigned* __restrict__ esr,
    const char* __restrict__ dout, const char* __restrict__ relrec,
    char* __restrict__ aggB,
    const float* __restrict__ w_alpha, const float* __restrict__ w_b, int M) {
  const int lane = threadIdx.x & 63;
  const int half = lane >> 5, hl = lane & 31;
  const int n = (int)(((size_t)blockIdx.x * blockDim.x + threadIdx.x) >> 6);
  if (n >= M) return;
  const float LOG2E = 1.44269504f;
  const f4 wa = ((const f4*)w_alpha)[hl] * LOG2E;
  const float bb = w_b[0] * LOG2E;
  const int beg = offsets[n], end = offsets[n + 1];
  f4 acc = {0.f, 0.f, 0.f, 0.f};

  for (int i = beg + half; i < end; i += 2) {
    unsigned u = esr[i];
    int sub = (int)(u & 0x1FFFF), rel = (int)(u >> 17);
    const char* rs = dout + (size_t)sub * 512;
    const char* rr = relrec + (size_t)rel * 512;

    ushort4 h = *(const ushort4*)(rs + hl * 8);
    unsigned asb = *(const unsigned*)(rs + 256 + hl * 4);
    ushort4 r = *(const ushort4*)(rr + hl * 8);
    unsigned arb = *(const unsigned*)(rr + 256 + hl * 4);

    f2 as_lo = __builtin_amdgcn_cvt_pk_f32_fp8(asb, false);
    f2 as_hi = __builtin_amdgcn_cvt_pk_f32_fp8(asb, true);
    f2 ar_lo = __builtin_amdgcn_cvt_pk_f32_fp8(arb, false);
    f2 ar_hi = __builtin_amdgcn_cvt_pk_f32_fp8(arb, true);

    float p = fmaxf(as_lo.x + ar_lo.x, 0.f) * wa.x +
              fmaxf(as_lo.y + ar_lo.y, 0.f) * wa.y +
              fmaxf(as_hi.x + ar_hi.x, 0.f) * wa.z +
              fmaxf(as_hi.y + ar_hi.y, 0.f) * wa.w;
#pragma unroll
    for (int off = 16; off > 0; off >>= 1) p += __shfl_xor(p, off, 64);
    const float alpha =
        __builtin_amdgcn_rcpf(1.f + __builtin_amdgcn_exp2f(-(p + bb)));

    f4 m = {bf2f(h.x) + bf2f(r.x), bf2f(h.y) + bf2f(r.y),
            bf2f(h.z) + bf2f(r.z), bf2f(h.w) + bf2f(r.w)};
    acc += alpha * m;
  }

  acc.x += __shfl_xor(acc.x, 32, 64);
  acc.y += __shfl_xor(acc.y, 32, 64);
  acc.z += __shfl_xor(acc.z, 32, 64);
  acc.w += __shfl_xor(acc.w, 32, 64);
  if (half == 0) {
    ushort4 o;
    o.x = f2bf(acc.x); o.y = f2bf(acc.y); o.z = f2bf(acc.z); o.w = f2bf(acc.w);
    *(ushort4*)(aggB + (size_t)n * 256 + hl * 8) = o;
  }
}

extern "C" void kernel_launch(void* const* d_in, const int* in_sizes, int n_in,
                              void* d_out, int out_size, void* d_ws, size_t ws_size,
                              hipStream_t stream) {
  const float* hidden = (const float*)d_in[0];
  const int* edges = (const int*)d_in[1];
  const float* rela = (const float*)d_in[4];
  const float* Ws = (const float*)d_in[5];
  const float* Wr = (const float*)d_in[6];
  const float* wa = (const float*)d_in[7];
  const float* wb = (const float*)d_in[8];
  const float* Wh = (const float*)d_in[9];

  const int M = in_sizes[0] / 128;     // 50000
  const int n_edge = in_sizes[1] / 6;  // 640000
  const int relv = in_sizes[4] / 128;  // 1003
  const int NB = (M + 255) / 256;

  char* ws = (char*)d_ws;
  size_t off = 0;
  char* relrec = ws; off += (size_t)relv * 512;
  unsigned short* WsT = (unsigned short*)(ws + off); off += 32768;
  unsigned short* WrT = (unsigned short*)(ws + off); off += 32768;
  unsigned short* WhT = (unsigned short*)(ws + off); off += 32768;
  unsigned* esr = (unsigned*)(ws + off); off += (size_t)n_edge * 4;
  char* aggB = ws + off; off += (size_t)M * 256;
  int* counts = (int*)(ws + off); off += (size_t)M * 4;
  int* offsets = (int*)(ws + off); off += (size_t)(M + 1) * 4;
  int* cursor = (int*)(ws + off); off += (size_t)M * 4;
  int* bsums = (int*)(ws + off); off += 1024;
  int* bpref = (int*)(ws + off);
  char* dout = (char*)d_out;

  hipMemsetAsync(counts, 0, (size_t)M * 4, stream);

  const int BH = (M * 16 + 255) / 256, BR = (relv * 16 + 255) / 256;
  const int BE = (n_edge + 255) / 256;
  prep<<<BH + BR + 192 + BE, 256, 0, stream>>>(hidden, rela, Ws, Wr, Wh, edges,
                                               n_edge, dout, relrec, WsT, WrT,
                                               WhT, counts, M, relv);

  // As_fp8 -> dout bytes [256,384); Ar_fp8 -> relrec bytes [256,384)
  gemm_mfma<1><<<(M + 63) / 64, 256, 0, stream>>>(dout, 512, WsT, dout + 256, 512, M);
  gemm_mfma<1><<<(relv + 63) / 64, 256, 0, stream>>>(relrec, 512, WrT, relrec + 256, 512, relv);

  scan_reduce<<<NB, 256, 0, stream>>>(counts, M, bsums);
  scan_sums<<<1, 256, 0, stream>>>(bsums, NB, bpref);
  scan_final<<<NB, 256, 0, stream>>>(counts, M, n_edge, bpref, offsets, cursor);
  scatter_kernel<<<BE, 256, 0, stream>>>(edges, n_edge, cursor, esr);

  node_agg<<<((size_t)M * 64 + 255) / 256, 256, 0, stream>>>(offsets, esr, dout,
                                                             relrec, aggB, wa, wb, M);

  gemm_mfma<0><<<(M + 63) / 64, 256, 0, stream>>>(aggB, 256, WhT, dout, 512, M);
}

// Round 6
// 157.213 us; speedup vs baseline: 4.3598x; 1.0630x over previous
//
#include <hip/hip_runtime.h>

typedef float f4 __attribute__((ext_vector_type(4)));
typedef float f2 __attribute__((ext_vector_type(2)));
typedef float f8 __attribute__((ext_vector_type(8)));
typedef float f32x4 __attribute__((ext_vector_type(4)));
typedef short bf16x8 __attribute__((ext_vector_type(8)));
typedef unsigned short u16x8 __attribute__((ext_vector_type(8)));

__device__ inline float bf2f(unsigned short u) {
  return __uint_as_float(((unsigned)u) << 16);
}
__device__ inline unsigned short f2bf(float f) {
  unsigned u = __float_as_uint(f);
  return (unsigned short)((u + 0x7FFF + ((u >> 16) & 1)) >> 16);
}
__device__ inline u16x8 cvt8(const float* __restrict__ src) {
  f4 lo = *(const f4*)src, hi = *(const f4*)(src + 4);
  u16x8 v;
  v[0] = f2bf(lo.x); v[1] = f2bf(lo.y); v[2] = f2bf(lo.z); v[3] = f2bf(lo.w);
  v[4] = f2bf(hi.x); v[5] = f2bf(hi.y); v[6] = f2bf(hi.z); v[7] = f2bf(hi.w);
  return v;
}

// Fused: hidden->bf16 into d_out record [0,256); rela->bf16 into relrec [0,256);
// 3x weight transpose+convert; edge histogram + packed edge emit.
__global__ __launch_bounds__(256) void prep(
    const float* __restrict__ hidden, const float* __restrict__ rela,
    const float* __restrict__ Ws, const float* __restrict__ Wr,
    const float* __restrict__ Wh, const int* __restrict__ edges, int n_edge,
    char* __restrict__ dout, char* __restrict__ relrec,
    unsigned short* __restrict__ WsT, unsigned short* __restrict__ WrT,
    unsigned short* __restrict__ WhT, int* __restrict__ counts,
    uint2* __restrict__ epk, int M, int relv) {
  const int t = threadIdx.x;
  const int BH = (M * 16 + 255) >> 8;
  const int BR = (relv * 16 + 255) >> 8;
  int b = blockIdx.x;
  if (b < BH) {
    int c = b * 256 + t;
    if (c < M * 16) {
      int row = c >> 4, part = c & 15;
      u16x8 v = cvt8(hidden + (size_t)row * 128 + part * 8);
      *(u16x8*)(dout + (size_t)row * 512 + part * 16) = v;
    }
    return;
  }
  b -= BH;
  if (b < BR) {
    int c = b * 256 + t;
    if (c < relv * 16) {
      int row = c >> 4, part = c & 15;
      u16x8 v = cvt8(rela + (size_t)row * 128 + part * 8);
      *(u16x8*)(relrec + (size_t)row * 512 + part * 16) = v;
    }
    return;
  }
  b -= BR;
  if (b < 192) {
    int wsel = b >> 6;
    const float* W = wsel == 0 ? Ws : (wsel == 1 ? Wr : Wh);
    unsigned short* WT = wsel == 0 ? WsT : (wsel == 1 ? WrT : WhT);
    int e = (b & 63) * 256 + t;  // 0..16383
    int cc = e >> 7, kk = e & 127;
    WT[e] = f2bf(W[kk * 128 + cc]);  // WT[c][k] = W[k][c]
    return;
  }
  b -= 192;
  int e = b * 256 + t;
  if (e < n_edge) {
    int2 a = *(const int2*)(edges + (size_t)e * 6 + 2);  // rel, 0
    int2 so = *(const int2*)(edges + (size_t)e * 6 + 4); // sub, obj
    atomicAdd(&counts[so.y], 1);
    epk[e] = make_uint2((unsigned)so.x | ((unsigned)a.x << 17), (unsigned)so.y);
  }
}

// Tile body: out = A_bf16[64 rows,128] @ W via WT (bf16 [c][k]) + MFMA 16x16x32.
// MODE 0: f32 out at row*outStride + col*4;  MODE 1: fp8 e4m3 at row*outStride + col.
template <int MODE>
__device__ inline void gemm_body(const char* __restrict__ Ab, int aStride,
                                 const unsigned short* __restrict__ WT,
                                 char* __restrict__ outB, int outStride, int M,
                                 int row0, char* lds) {
  const int t = threadIdx.x;
#pragma unroll
  for (int i = 0; i < 8; ++i) {
    int m = i * 256 + t;
    u16x8 v = ((const u16x8*)WT)[m];
    *(u16x8*)(lds + 16384 + ((m * 16) ^ (((m >> 4) & 7) << 4))) = v;
  }
#pragma unroll
  for (int i = 0; i < 4; ++i) {
    int m = i * 256 + t;
    int r = m >> 4;
    int gr = row0 + r;
    if (gr > M - 1) gr = M - 1;
    u16x8 v = *(const u16x8*)(Ab + (size_t)gr * aStride + (m & 15) * 16);
    *(u16x8*)(lds + ((m * 16) ^ ((r & 7) << 4))) = v;
  }
  __syncthreads();

  const int w = t >> 6, l = t & 63, lr = l & 15, lg = l >> 4;
  const int rowA = w * 16 + lr;
  f32x4 acc[8] = {};
#pragma unroll
  for (int k0 = 0; k0 < 4; ++k0) {
    int kb = k0 * 64 + lg * 16;
    bf16x8 a = *(const bf16x8*)(lds + rowA * 256 + (kb ^ ((rowA & 7) << 4)));
#pragma unroll
    for (int c0 = 0; c0 < 8; ++c0) {
      int cr = c0 * 16 + lr;
      bf16x8 bfr = *(const bf16x8*)(lds + 16384 + cr * 256 + (kb ^ ((cr & 7) << 4)));
      acc[c0] = __builtin_amdgcn_mfma_f32_16x16x32_bf16(a, bfr, acc[c0], 0, 0, 0);
    }
  }
#pragma unroll
  for (int c0 = 0; c0 < 8; ++c0) {
    int col = c0 * 16 + lr;
#pragma unroll
    for (int j = 0; j < 4; ++j) {
      int grow = row0 + w * 16 + lg * 4 + j;
      if (grow < M) {
        if (MODE == 0) {
          *(float*)(outB + (size_t)grow * outStride + (size_t)col * 4) = acc[c0][j];
        } else {
          unsigned pk = __builtin_amdgcn_cvt_pk_fp8_f32(acc[c0][j], acc[c0][j], 0, false);
          *(unsigned char*)(outB + (size_t)grow * outStride + col) = (unsigned char)pk;
        }
      }
    }
  }
}

__global__ __launch_bounds__(256) void gemm_fp8_dual(
    const char* __restrict__ A1, const unsigned short* __restrict__ WT1,
    char* __restrict__ o1, int M1, int nb1,
    const char* __restrict__ A2, const unsigned short* __restrict__ WT2,
    char* __restrict__ o2, int M2) {
  __shared__ __align__(16) char lds[49152];
  if ((int)blockIdx.x < nb1)
    gemm_body<1>(A1, 512, WT1, o1, 512, M1, blockIdx.x * 64, lds);
  else
    gemm_body<1>(A2, 512, WT2, o2, 512, M2, ((int)blockIdx.x - nb1) * 64, lds);
}

__global__ __launch_bounds__(256) void gemm_f32(const char* __restrict__ A,
                                                const unsigned short* __restrict__ WT,
                                                char* __restrict__ o, int M) {
  __shared__ __align__(16) char lds[49152];
  gemm_body<0>(A, 256, WT, o, 512, M, blockIdx.x * 64, lds);
}

// Single-pass exclusive scan, decoupled lookback. status[b] = flag<<30 | value.
__global__ __launch_bounds__(256) void scan_lookback(
    const int* __restrict__ counts, int M, int n_edge, int* __restrict__ status,
    int* __restrict__ offsets, int* __restrict__ cursor) {
  const int t = threadIdx.x, b = blockIdx.x;
  const int idx = b * 256 + t;
  int c = (idx < M) ? counts[idx] : 0;
  const int lane = t & 63, w = t >> 6;
  int s = c;
  for (int off = 1; off < 64; off <<= 1) {
    int o = __shfl_up(s, off, 64);
    if (lane >= off) s += o;
  }
  __shared__ int wsum[4], wpre[4];
  __shared__ int blk_prefix;
  if (lane == 63) wsum[w] = s;
  __syncthreads();
  if (t == 0) {
    int r = 0;
#pragma unroll
    for (int i = 0; i < 4; ++i) { wpre[i] = r; r += wsum[i]; }
    unsigned pub = ((b == 0 ? 2u : 1u) << 30) | (unsigned)r;
    __hip_atomic_store(&status[b], (int)pub, __ATOMIC_RELEASE, __HIP_MEMORY_SCOPE_AGENT);
    if (b == 0) blk_prefix = 0;
  }
  __syncthreads();
  if (b > 0 && w == 0) {
    int prefix = 0;
    int k = b - 1;
    for (;;) {
      int j = k - lane;
      unsigned v;
      if (j >= 0) {
        do {
          v = (unsigned)__hip_atomic_load(&status[j], __ATOMIC_ACQUIRE,
                                          __HIP_MEMORY_SCOPE_AGENT);
        } while ((v >> 30) == 0u);
      } else {
        v = 2u << 30;
      }
      int val = (int)(v & 0x3FFFFFFFu);
      unsigned long long incl = __ballot((v >> 30) == 2u);
      int l = (int)__ffsll(incl) - 1;
      int contrib = (l >= 0) ? ((lane <= l) ? val : 0) : val;
#pragma unroll
      for (int off = 32; off; off >>= 1) contrib += __shfl_xor(contrib, off, 64);
      prefix += contrib;
      if (l >= 0) break;
      k -= 64;
    }
    if (lane == 0) {
      blk_prefix = prefix;
      int total = wpre[3] + wsum[3];
      __hip_atomic_store(&status[b], (int)((2u << 30) | (unsigned)(prefix + total)),
                         __ATOMIC_RELEASE, __HIP_MEMORY_SCOPE_AGENT);
    }
  }
  __syncthreads();
  int excl = blk_prefix + wpre[w] + s - c;
  if (idx < M) { offsets[idx] = excl; cursor[idx] = excl; }
  if (idx == 0) offsets[M] = n_edge;
}

__global__ __launch_bounds__(256) void scatter_kernel(const uint2* __restrict__ epk,
                                                      int n_edge, int* __restrict__ cursor,
                                                      unsigned* __restrict__ esr) {
  int e = blockIdx.x * 256 + threadIdx.x;
  if (e < n_edge) {
    uint2 pe = epk[e];
    int pos = atomicAdd(&cursor[pe.y], 1);
    esr[pos] = pe.x;
  }
}

__device__ inline float edge_alpha16(uint2 as, uint2 ar, const f8& wa, float bb) {
  f2 a0 = __builtin_amdgcn_cvt_pk_f32_fp8(as.x, false);
  f2 a1 = __builtin_amdgcn_cvt_pk_f32_fp8(as.x, true);
  f2 a2 = __builtin_amdgcn_cvt_pk_f32_fp8(as.y, false);
  f2 a3 = __builtin_amdgcn_cvt_pk_f32_fp8(as.y, true);
  f2 r0 = __builtin_amdgcn_cvt_pk_f32_fp8(ar.x, false);
  f2 r1 = __builtin_amdgcn_cvt_pk_f32_fp8(ar.x, true);
  f2 r2 = __builtin_amdgcn_cvt_pk_f32_fp8(ar.y, false);
  f2 r3 = __builtin_amdgcn_cvt_pk_f32_fp8(ar.y, true);
  float p = fmaxf(a0.x + r0.x, 0.f) * wa[0] + fmaxf(a0.y + r0.y, 0.f) * wa[1] +
            fmaxf(a1.x + r1.x, 0.f) * wa[2] + fmaxf(a1.y + r1.y, 0.f) * wa[3] +
            fmaxf(a2.x + r2.x, 0.f) * wa[4] + fmaxf(a2.y + r2.y, 0.f) * wa[5] +
            fmaxf(a3.x + r3.x, 0.f) * wa[6] + fmaxf(a3.y + r3.y, 0.f) * wa[7];
#pragma unroll
  for (int off = 1; off <= 8; off <<= 1) p += __shfl_xor(p, off, 64);
  return __builtin_amdgcn_rcpf(1.f + __builtin_amdgcn_exp2f(-(p + bb)));
}

__device__ inline f8 msg8(u16x8 h, u16x8 r) {
  f8 m;
#pragma unroll
  for (int j = 0; j < 8; ++j) m[j] = bf2f((unsigned short)h[j]) + bf2f((unsigned short)r[j]);
  return m;
}

// Wave = 1 node; 4x16-lane groups each own every-4th edge, unrolled x2
// (up to 8 edges' gathers in flight per wave). Lane gl covers dims [gl*8, gl*8+8).
__global__ __launch_bounds__(256) void node_agg(
    const int* __restrict__ offsets, const unsigned* __restrict__ esr,
    const char* __restrict__ dout, const char* __restrict__ relrec,
    char* __restrict__ aggB,
    const float* __restrict__ w_alpha, const float* __restrict__ w_b, int M) {
  const int lane = threadIdx.x & 63;
  const int g = lane >> 4, gl = lane & 15;
  const int n = (int)(((size_t)blockIdx.x * blockDim.x + threadIdx.x) >> 6);
  if (n >= M) return;
  const float LOG2E = 1.44269504f;
  f8 wa;
  {
    f4 lo = ((const f4*)w_alpha)[gl * 2], hi = ((const f4*)w_alpha)[gl * 2 + 1];
    wa[0] = lo.x; wa[1] = lo.y; wa[2] = lo.z; wa[3] = lo.w;
    wa[4] = hi.x; wa[5] = hi.y; wa[6] = hi.z; wa[7] = hi.w;
    wa *= LOG2E;
  }
  const float bb = w_b[0] * LOG2E;
  const int beg = offsets[n], end = offsets[n + 1];
  f8 acc = {0.f, 0.f, 0.f, 0.f, 0.f, 0.f, 0.f, 0.f};

  for (int i = beg + g; i < end; i += 8) {
    const int i2 = i + 4;
    const bool has2 = i2 < end;
    unsigned u1 = esr[i];
    unsigned u2 = has2 ? esr[i2] : u1;

    const char* rs1 = dout + (size_t)(u1 & 0x1FFFF) * 512;
    const char* rr1 = relrec + (size_t)(u1 >> 17) * 512;
    const char* rs2 = dout + (size_t)(u2 & 0x1FFFF) * 512;
    const char* rr2 = relrec + (size_t)(u2 >> 17) * 512;

    u16x8 h1 = *(const u16x8*)(rs1 + gl * 16);
    uint2 as1 = *(const uint2*)(rs1 + 256 + gl * 8);
    u16x8 r1 = *(const u16x8*)(rr1 + gl * 16);
    uint2 ar1 = *(const uint2*)(rr1 + 256 + gl * 8);
    u16x8 h2 = *(const u16x8*)(rs2 + gl * 16);
    uint2 as2 = *(const uint2*)(rs2 + 256 + gl * 8);
    u16x8 r2 = *(const u16x8*)(rr2 + gl * 16);
    uint2 ar2 = *(const uint2*)(rr2 + 256 + gl * 8);

    float alpha1 = edge_alpha16(as1, ar1, wa, bb);
    float alpha2 = edge_alpha16(as2, ar2, wa, bb);
    if (!has2) alpha2 = 0.f;

    acc += alpha1 * msg8(h1, r1);
    acc += alpha2 * msg8(h2, r2);
  }

#pragma unroll
  for (int j = 0; j < 8; ++j) {
    acc[j] += __shfl_xor(acc[j], 16, 64);
    acc[j] += __shfl_xor(acc[j], 32, 64);
  }
  if (g == 0) {
    u16x8 o;
#pragma unroll
    for (int j = 0; j < 8; ++j) o[j] = f2bf(acc[j]);
    *(u16x8*)(aggB + (size_t)n * 256 + gl * 16) = o;
  }
}

extern "C" void kernel_launch(void* const* d_in, const int* in_sizes, int n_in,
                              void* d_out, int out_size, void* d_ws, size_t ws_size,
                              hipStream_t stream) {
  const float* hidden = (const float*)d_in[0];
  const int* edges = (const int*)d_in[1];
  const float* rela = (const float*)d_in[4];
  const float* Ws = (const float*)d_in[5];
  const float* Wr = (const float*)d_in[6];
  const float* wa = (const float*)d_in[7];
  const float* wb = (const float*)d_in[8];
  const float* Wh = (const float*)d_in[9];

  const int M = in_sizes[0] / 128;     // 50000
  const int n_edge = in_sizes[1] / 6;  // 640000
  const int relv = in_sizes[4] / 128;  // 1003
  const int NB = (M + 255) / 256;      // 196

  char* ws = (char*)d_ws;
  size_t off = 0;
  char* relrec = ws; off += (size_t)relv * 512;
  unsigned short* WsT = (unsigned short*)(ws + off); off += 32768;
  unsigned short* WrT = (unsigned short*)(ws + off); off += 32768;
  unsigned short* WhT = (unsigned short*)(ws + off); off += 32768;
  unsigned* esr = (unsigned*)(ws + off); off += (size_t)n_edge * 4;
  uint2* epk = (uint2*)(ws + off); off += (size_t)n_edge * 8;
  char* aggB = ws + off; off += (size_t)M * 256;
  int* counts = (int*)(ws + off); off += (size_t)M * 4;
  int* status = (int*)(ws + off); off += 1024;
  int* offsets = (int*)(ws + off); off += (size_t)(M + 1) * 4;
  int* cursor = (int*)(ws + off);
  char* dout = (char*)d_out;

  // zero counts + status in one memset (contiguous)
  hipMemsetAsync(counts, 0, (size_t)M * 4 + 1024, stream);

  const int BH = (M * 16 + 255) / 256, BR = (relv * 16 + 255) / 256;
  const int BE = (n_edge + 255) / 256;
  prep<<<BH + BR + 192 + BE, 256, 0, stream>>>(hidden, rela, Ws, Wr, Wh, edges,
                                               n_edge, dout, relrec, WsT, WrT,
                                               WhT, counts, epk, M, relv);

  const int nb1 = (M + 63) / 64;
  gemm_fp8_dual<<<nb1 + (relv + 63) / 64, 256, 0, stream>>>(
      dout, WsT, dout + 256, M, nb1, relrec, WrT, relrec + 256, relv);

  scan_lookback<<<NB, 256, 0, stream>>>(counts, M, n_edge, status, offsets, cursor);
  scatter_kernel<<<BE, 256, 0, stream>>>(epk, n_edge, cursor, esr);

  node_agg<<<((size_t)M * 64 + 255) / 256, 256, 0, stream>>>(offsets, esr, dout,
                                                             relrec, aggB, wa, wb, M);

  gemm_f32<<<(M + 63) / 64, 256, 0, stream>>>(aggB, WhT, dout, M);
}

// Round 7
// 152.393 us; speedup vs baseline: 4.4977x; 1.0316x over previous
//
#include <hip/hip_runtime.h>

typedef float f4 __attribute__((ext_vector_type(4)));
typedef float f2 __attribute__((ext_vector_type(2)));
typedef float f8 __attribute__((ext_vector_type(8)));
typedef float f32x4 __attribute__((ext_vector_type(4)));
typedef short bf16x8 __attribute__((ext_vector_type(8)));
typedef unsigned short u16x8 __attribute__((ext_vector_type(8)));

__device__ inline float bf2f(unsigned short u) {
  return __uint_as_float(((unsigned)u) << 16);
}
__device__ inline unsigned short f2bf(float f) {
  unsigned u = __float_as_uint(f);
  return (unsigned short)((u + 0x7FFF + ((u >> 16) & 1)) >> 16);
}

// prep: 3 weight transposes (f32 -> bf16, WT[c][k] = W[k][c]) + edge histogram
__global__ __launch_bounds__(256) void prep(
    const float* __restrict__ Ws, const float* __restrict__ Wr,
    const float* __restrict__ Wh, const int* __restrict__ edges, int n_edge,
    unsigned short* __restrict__ WsT, unsigned short* __restrict__ WrT,
    unsigned short* __restrict__ WhT, int* __restrict__ counts) {
  const int t = threadIdx.x;
  int b = blockIdx.x;
  if (b < 192) {
    int wsel = b >> 6;
    const float* W = wsel == 0 ? Ws : (wsel == 1 ? Wr : Wh);
    unsigned short* WT = wsel == 0 ? WsT : (wsel == 1 ? WrT : WhT);
    int e = (b & 63) * 256 + t;  // 0..16383
    int cc = e >> 7, kk = e & 127;
    WT[e] = f2bf(W[kk * 128 + cc]);
    return;
  }
  b -= 192;
  int e = b * 256 + t;
  if (e < n_edge) atomicAdd(&counts[edges[e * 6 + 5]], 1);
}

// Dual-output GEMM: for a 64-row f32 tile of src, computes
//   A' = src @ Wx  -> fp8 e4m3  at out + row*384 + 256  (128 B)
//   P' = src @ Wh  -> bf16      at out + row*384        (256 B)
// Node blocks use (hidden, WsT) -> rec; rel blocks use (rela, WrT) -> relrec.
__global__ __launch_bounds__(256) void gemm_dual(
    const float* __restrict__ hidden, int M, int nbN,
    const float* __restrict__ rela, int relv,
    const unsigned short* __restrict__ WsT, const unsigned short* __restrict__ WrT,
    const unsigned short* __restrict__ WhT,
    char* __restrict__ rec, char* __restrict__ relrec) {
  __shared__ __align__(16) char lds[81920];  // A 16K | Wx 32K | Wh 32K
  const int t = threadIdx.x;
  int b = blockIdx.x;
  const float* src;
  const unsigned short* WxT;
  char* out;
  int rows, row0;
  if (b < nbN) { src = hidden; WxT = WsT; out = rec; rows = M; row0 = b * 64; }
  else { src = rela; WxT = WrT; out = relrec; rows = relv; row0 = (b - nbN) * 64; }

#pragma unroll
  for (int i = 0; i < 8; ++i) {
    int m = i * 256 + t;
    int sw = (m * 16) ^ (((m >> 4) & 7) << 4);
    *(u16x8*)(lds + 16384 + sw) = ((const u16x8*)WxT)[m];
    *(u16x8*)(lds + 49152 + sw) = ((const u16x8*)WhT)[m];
  }
#pragma unroll
  for (int i = 0; i < 4; ++i) {
    int m = i * 256 + t;
    int r = m >> 4, c = m & 15;
    int gr = row0 + r;
    if (gr > rows - 1) gr = rows - 1;
    const float* s = src + (size_t)gr * 128 + c * 8;
    f4 lo = *(const f4*)s, hi = *(const f4*)(s + 4);
    u16x8 v;
    v[0] = f2bf(lo.x); v[1] = f2bf(lo.y); v[2] = f2bf(lo.z); v[3] = f2bf(lo.w);
    v[4] = f2bf(hi.x); v[5] = f2bf(hi.y); v[6] = f2bf(hi.z); v[7] = f2bf(hi.w);
    *(u16x8*)(lds + ((m * 16) ^ ((r & 7) << 4))) = v;
  }
  __syncthreads();

  const int w = t >> 6, l = t & 63, lr = l & 15, lg = l >> 4;
  const int rowA = w * 16 + lr;
  bf16x8 afr[4];
#pragma unroll
  for (int k0 = 0; k0 < 4; ++k0)
    afr[k0] = *(const bf16x8*)(lds + rowA * 256 + ((k0 * 64 + lg * 16) ^ ((rowA & 7) << 4)));

  // pass 1: Wx -> fp8
  {
    f32x4 acc[8] = {};
#pragma unroll
    for (int k0 = 0; k0 < 4; ++k0) {
      int kb = k0 * 64 + lg * 16;
#pragma unroll
      for (int c0 = 0; c0 < 8; ++c0) {
        int cr = c0 * 16 + lr;
        bf16x8 bfr = *(const bf16x8*)(lds + 16384 + cr * 256 + (kb ^ ((cr & 7) << 4)));
        acc[c0] = __builtin_amdgcn_mfma_f32_16x16x32_bf16(afr[k0], bfr, acc[c0], 0, 0, 0);
      }
    }
#pragma unroll
    for (int c0 = 0; c0 < 8; ++c0) {
      int col = c0 * 16 + lr;
#pragma unroll
      for (int j = 0; j < 4; ++j) {
        int grow = row0 + w * 16 + lg * 4 + j;
        if (grow < rows) {
          unsigned pk = __builtin_amdgcn_cvt_pk_fp8_f32(acc[c0][j], acc[c0][j], 0, false);
          *(unsigned char*)(out + (size_t)grow * 384 + 256 + col) = (unsigned char)pk;
        }
      }
    }
  }
  // pass 2: Wh -> bf16
  {
    f32x4 acc[8] = {};
#pragma unroll
    for (int k0 = 0; k0 < 4; ++k0) {
      int kb = k0 * 64 + lg * 16;
#pragma unroll
      for (int c0 = 0; c0 < 8; ++c0) {
        int cr = c0 * 16 + lr;
        bf16x8 bfr = *(const bf16x8*)(lds + 49152 + cr * 256 + (kb ^ ((cr & 7) << 4)));
        acc[c0] = __builtin_amdgcn_mfma_f32_16x16x32_bf16(afr[k0], bfr, acc[c0], 0, 0, 0);
      }
    }
#pragma unroll
    for (int c0 = 0; c0 < 8; ++c0) {
      int col = c0 * 16 + lr;
#pragma unroll
      for (int j = 0; j < 4; ++j) {
        int grow = row0 + w * 16 + lg * 4 + j;
        if (grow < rows)
          *(unsigned short*)(out + (size_t)grow * 384 + col * 2) = f2bf(acc[c0][j]);
      }
    }
  }
}

// Single-pass exclusive scan, decoupled lookback. status[b] = flag<<30 | value.
__global__ __launch_bounds__(256) void scan_lookback(
    const int* __restrict__ counts, int M, int n_edge, int* __restrict__ status,
    int* __restrict__ offsets, int* __restrict__ cursor) {
  const int t = threadIdx.x, b = blockIdx.x;
  const int idx = b * 256 + t;
  int c = (idx < M) ? counts[idx] : 0;
  const int lane = t & 63, w = t >> 6;
  int s = c;
  for (int off = 1; off < 64; off <<= 1) {
    int o = __shfl_up(s, off, 64);
    if (lane >= off) s += o;
  }
  __shared__ int wsum[4], wpre[4];
  __shared__ int blk_prefix;
  if (lane == 63) wsum[w] = s;
  __syncthreads();
  if (t == 0) {
    int r = 0;
#pragma unroll
    for (int i = 0; i < 4; ++i) { wpre[i] = r; r += wsum[i]; }
    unsigned pub = ((b == 0 ? 2u : 1u) << 30) | (unsigned)r;
    __hip_atomic_store(&status[b], (int)pub, __ATOMIC_RELEASE, __HIP_MEMORY_SCOPE_AGENT);
    if (b == 0) blk_prefix = 0;
  }
  __syncthreads();
  if (b > 0 && w == 0) {
    int prefix = 0;
    int k = b - 1;
    for (;;) {
      int j = k - lane;
      unsigned v;
      if (j >= 0) {
        do {
          v = (unsigned)__hip_atomic_load(&status[j], __ATOMIC_ACQUIRE,
                                          __HIP_MEMORY_SCOPE_AGENT);
        } while ((v >> 30) == 0u);
      } else {
        v = 2u << 30;
      }
      int val = (int)(v & 0x3FFFFFFFu);
      unsigned long long incl = __ballot((v >> 30) == 2u);
      int l = (int)__ffsll(incl) - 1;
      int contrib = (l >= 0) ? ((lane <= l) ? val : 0) : val;
#pragma unroll
      for (int off = 32; off; off >>= 1) contrib += __shfl_xor(contrib, off, 64);
      prefix += contrib;
      if (l >= 0) break;
      k -= 64;
    }
    if (lane == 0) {
      blk_prefix = prefix;
      int total = wpre[3] + wsum[3];
      __hip_atomic_store(&status[b], (int)((2u << 30) | (unsigned)(prefix + total)),
                         __ATOMIC_RELEASE, __HIP_MEMORY_SCOPE_AGENT);
    }
  }
  __syncthreads();
  int excl = blk_prefix + wpre[w] + s - c;
  if (idx < M) { offsets[idx] = excl; cursor[idx] = excl; }
  if (idx == 0) offsets[M] = n_edge;
}

// CSR scatter; emits pre-scaled byte offsets (sub*384, rel*384).
__global__ __launch_bounds__(256) void scatter_kernel(const int* __restrict__ edges,
                                                      int n_edge, int* __restrict__ cursor,
                                                      uint2* __restrict__ esr2) {
  int e = blockIdx.x * 256 + threadIdx.x;
  if (e < n_edge) {
    int rel = edges[(size_t)e * 6 + 2];
    int2 so = *(const int2*)(edges + (size_t)e * 6 + 4);  // sub, obj
    int pos = atomicAdd(&cursor[so.y], 1);
    esr2[pos] = make_uint2((unsigned)(so.x * 384), (unsigned)(rel * 384));
  }
}

__device__ inline float edge_alpha16(uint2 as, uint2 ar, const f8& wa, float bb) {
  f2 a0 = __builtin_amdgcn_cvt_pk_f32_fp8(as.x, false);
  f2 a1 = __builtin_amdgcn_cvt_pk_f32_fp8(as.x, true);
  f2 a2 = __builtin_amdgcn_cvt_pk_f32_fp8(as.y, false);
  f2 a3 = __builtin_amdgcn_cvt_pk_f32_fp8(as.y, true);
  f2 r0 = __builtin_amdgcn_cvt_pk_f32_fp8(ar.x, false);
  f2 r1 = __builtin_amdgcn_cvt_pk_f32_fp8(ar.x, true);
  f2 r2 = __builtin_amdgcn_cvt_pk_f32_fp8(ar.y, false);
  f2 r3 = __builtin_amdgcn_cvt_pk_f32_fp8(ar.y, true);
  float p = fmaxf(a0.x + r0.x, 0.f) * wa[0] + fmaxf(a0.y + r0.y, 0.f) * wa[1] +
            fmaxf(a1.x + r1.x, 0.f) * wa[2] + fmaxf(a1.y + r1.y, 0.f) * wa[3] +
            fmaxf(a2.x + r2.x, 0.f) * wa[4] + fmaxf(a2.y + r2.y, 0.f) * wa[5] +
            fmaxf(a3.x + r3.x, 0.f) * wa[6] + fmaxf(a3.y + r3.y, 0.f) * wa[7];
#pragma unroll
  for (int off = 1; off <= 8; off <<= 1) p += __shfl_xor(p, off, 64);
  return __builtin_amdgcn_rcpf(1.f + __builtin_amdgcn_exp2f(-(p + bb)));
}

__device__ inline f8 msg8(u16x8 h, u16x8 r) {
  f8 m;
#pragma unroll
  for (int j = 0; j < 8; ++j)
    m[j] = bf2f((unsigned short)h[j]) + bf2f((unsigned short)r[j]);
  return m;
}

// Wave = 1 node; 4x16-lane groups, unroll x2. Messages are pre-transformed
// (H'=h@Wh, R'=r@Wh in bf16), so output is written f32 directly.
__global__ __launch_bounds__(256) void node_agg(
    const int* __restrict__ offsets, const uint2* __restrict__ esr2,
    const char* __restrict__ rec, const char* __restrict__ relrec,
    float* __restrict__ out,
    const float* __restrict__ w_alpha, const float* __restrict__ w_b, int M) {
  const int lane = threadIdx.x & 63;
  const int g = lane >> 4, gl = lane & 15;
  const int n = (int)((blockIdx.x * 256u + threadIdx.x) >> 6);
  if (n >= M) return;
  const unsigned bH = gl * 16u, bA = 256u + gl * 8u;
  const float LOG2E = 1.44269504f;
  f8 wa;
  {
    f4 lo = ((const f4*)w_alpha)[gl * 2], hi = ((const f4*)w_alpha)[gl * 2 + 1];
    wa[0] = lo.x; wa[1] = lo.y; wa[2] = lo.z; wa[3] = lo.w;
    wa[4] = hi.x; wa[5] = hi.y; wa[6] = hi.z; wa[7] = hi.w;
    wa *= LOG2E;
  }
  const float bb = w_b[0] * LOG2E;
  const int beg = offsets[n], end = offsets[n + 1];
  f8 acc = {0.f, 0.f, 0.f, 0.f, 0.f, 0.f, 0.f, 0.f};

  for (int i = beg + g; i < end; i += 8) {
    const bool has2 = (i + 4) < end;
    uint2 o1 = esr2[i];
    uint2 o2 = has2 ? esr2[i + 4] : o1;

    u16x8 h1 = *(const u16x8*)(rec + o1.x + bH);
    uint2 as1 = *(const uint2*)(rec + o1.x + bA);
    u16x8 r1 = *(const u16x8*)(relrec + o1.y + bH);
    uint2 ar1 = *(const uint2*)(relrec + o1.y + bA);
    u16x8 h2 = *(const u16x8*)(rec + o2.x + bH);
    uint2 as2 = *(const uint2*)(rec + o2.x + bA);
    u16x8 r2 = *(const u16x8*)(relrec + o2.y + bH);
    uint2 ar2 = *(const uint2*)(relrec + o2.y + bA);

    float alpha1 = edge_alpha16(as1, ar1, wa, bb);
    float alpha2 = edge_alpha16(as2, ar2, wa, bb);
    if (!has2) alpha2 = 0.f;

    acc += alpha1 * msg8(h1, r1);
    acc += alpha2 * msg8(h2, r2);
  }

#pragma unroll
  for (int j = 0; j < 8; ++j) {
    acc[j] += __shfl_xor(acc[j], 16, 64);
    acc[j] += __shfl_xor(acc[j], 32, 64);
  }
  if (g == 0) {
    f4 lo = {acc[0], acc[1], acc[2], acc[3]};
    f4 hi = {acc[4], acc[5], acc[6], acc[7]};
    float* dst = out + (size_t)n * 128 + gl * 8;
    *(f4*)dst = lo;
    *(f4*)(dst + 4) = hi;
  }
}

extern "C" void kernel_launch(void* const* d_in, const int* in_sizes, int n_in,
                              void* d_out, int out_size, void* d_ws, size_t ws_size,
                              hipStream_t stream) {
  const float* hidden = (const float*)d_in[0];
  const int* edges = (const int*)d_in[1];
  const float* rela = (const float*)d_in[4];
  const float* Ws = (const float*)d_in[5];
  const float* Wr = (const float*)d_in[6];
  const float* wa = (const float*)d_in[7];
  const float* wb = (const float*)d_in[8];
  const float* Wh = (const float*)d_in[9];

  const int M = in_sizes[0] / 128;     // 50000
  const int n_edge = in_sizes[1] / 6;  // 640000
  const int relv = in_sizes[4] / 128;  // 1003
  const int NB = (M + 255) / 256;      // scan blocks
  const int BE = (n_edge + 255) / 256;

  char* ws = (char*)d_ws;
  size_t off = 0;
  char* rec = ws; off += ((size_t)M * 384 + 255) & ~255ull;
  char* relrec = ws + off; off += ((size_t)relv * 384 + 255) & ~255ull;
  unsigned short* WsT = (unsigned short*)(ws + off); off += 32768;
  unsigned short* WrT = (unsigned short*)(ws + off); off += 32768;
  unsigned short* WhT = (unsigned short*)(ws + off); off += 32768;
  uint2* esr2 = (uint2*)(ws + off); off += (size_t)n_edge * 8;
  int* counts = (int*)(ws + off); off += (size_t)M * 4;
  int* status = (int*)(ws + off); off += 4096;
  int* offsets = (int*)(ws + off); off += ((size_t)(M + 1) * 4 + 255) & ~255ull;
  int* cursor = (int*)(ws + off);
  float* out = (float*)d_out;

  // zero counts + status (contiguous)
  hipMemsetAsync(counts, 0, (size_t)M * 4 + 4096, stream);

  prep<<<192 + BE, 256, 0, stream>>>(Ws, Wr, Wh, edges, n_edge, WsT, WrT, WhT, counts);

  const int nbN = (M + 63) / 64;
  gemm_dual<<<nbN + (relv + 63) / 64, 256, 0, stream>>>(hidden, M, nbN, rela, relv,
                                                        WsT, WrT, WhT, rec, relrec);

  scan_lookback<<<NB, 256, 0, stream>>>(counts, M, n_edge, status, offsets, cursor);
  scatter_kernel<<<BE, 256, 0, stream>>>(edges, n_edge, cursor, esr2);

  node_agg<<<(M * 64 + 255) / 256, 256, 0, stream>>>(offsets, esr2, rec, relrec,
                                                     out, wa, wb, M);
}